// Round 18
// baseline (68.421 us; speedup 1.0000x reference)
//
#include <hip/hip_runtime.h>

#define M_DIM 8192
#define N_DIM 8192
#define K_DIM 256

typedef __attribute__((ext_vector_type(4))) int i32x4;
typedef __attribute__((ext_vector_type(4))) float f32x4;

// Barrier that waits only on LDS ops (lgkmcnt) — global stores/DMA stay in flight.
__device__ __forceinline__ void bar_lds() {
    asm volatile("s_waitcnt lgkmcnt(0)" ::: "memory");
    __builtin_amdgcn_sched_barrier(0);
    __builtin_amdgcn_s_barrier();
}

// T4 counted wait: all but the newest 4 vector-mem ops (the just-issued prefetch)
// retired -> current K-tile's DMA landed; prefetch stays in flight across barrier.
__device__ __forceinline__ void bar_vm4() {
    asm volatile("s_waitcnt vmcnt(4)" ::: "memory");
    __builtin_amdgcn_sched_barrier(0);
    __builtin_amdgcn_s_barrier();
}

__device__ __forceinline__ void bar_vm0() {
    asm volatile("s_waitcnt vmcnt(0) lgkmcnt(0)" ::: "memory");
    __builtin_amdgcn_sched_barrier(0);
    __builtin_amdgcn_s_barrier();
}

__device__ __forceinline__ void async_lds16(const signed char* g, signed char* l) {
    __builtin_amdgcn_global_load_lds(
        (const __attribute__((address_space(1))) void*)g,
        (__attribute__((address_space(3))) void*)l, 16, 0, 0);
}

// ---------------- absmax partials: 1024 blocks/tensor, 2 float4/thread, no loop ----------------
__global__ __launch_bounds__(256) void absmax_kernel(const float* __restrict__ x,
                                                     const float* __restrict__ y,
                                                     float* __restrict__ partial) {
    const float* p = (blockIdx.y == 0) ? x : y;
    const float4* p4 = (const float4*)p;
    const int half = (M_DIM * K_DIM) / 8;          // 262144 float4s per half
    int i = blockIdx.x * 256 + threadIdx.x;
    float4 v = p4[i];
    float4 u = p4[half + i];
    float m = fmaxf(fmaxf(fmaxf(fabsf(v.x), fabsf(v.y)), fmaxf(fabsf(v.z), fabsf(v.w))),
                    fmaxf(fmaxf(fabsf(u.x), fabsf(u.y)), fmaxf(fabsf(u.z), fabsf(u.w))));
    for (int off = 32; off > 0; off >>= 1)
        m = fmaxf(m, __shfl_down(m, off));
    __shared__ float sm[4];
    int wid = threadIdx.x >> 6;
    if ((threadIdx.x & 63) == 0) sm[wid] = m;
    __syncthreads();
    if (threadIdx.x == 0)
        partial[blockIdx.y * 1024 + blockIdx.x] = fmaxf(fmaxf(sm[0], sm[1]), fmaxf(sm[2], sm[3]));
}

// Dual block-wide max-reduce of the 2x1024 partials -> scales. blockDim must be 256.
__device__ __forceinline__ void load_scales(const float* __restrict__ partial,
                                            float& sx, float& sy, float* ssc) {
    const int tid = threadIdx.x;
    float mx = fmaxf(fmaxf(partial[tid], partial[tid + 256]),
                     fmaxf(partial[tid + 512], partial[tid + 768]));
    float my = fmaxf(fmaxf(partial[1024 + tid], partial[1024 + tid + 256]),
                     fmaxf(partial[1024 + tid + 512], partial[1024 + tid + 768]));
    for (int off = 32; off > 0; off >>= 1) {
        mx = fmaxf(mx, __shfl_down(mx, off));
        my = fmaxf(my, __shfl_down(my, off));
    }
    if ((tid & 63) == 0) { ssc[tid >> 6] = mx; ssc[4 + (tid >> 6)] = my; }
    __syncthreads();
    mx = fmaxf(fmaxf(ssc[0], ssc[1]), fmaxf(ssc[2], ssc[3]));
    my = fmaxf(fmaxf(ssc[4], ssc[5]), fmaxf(ssc[6], ssc[7]));
    sx = fmaxf(mx / 127.0f, 1e-12f);   // same op sequence as jnp
    sy = fmaxf(my / 127.0f, 1e-12f);
}

__device__ __forceinline__ int quant1(float v, float s) {
    float q = rintf(v / s);                      // RNE matches jnp.round; IEEE div matches t/s
    q = fmaxf(-127.0f, fminf(127.0f, q));
    return (int)q;
}

// ---------------- fused quantize: x -> xq [M][K], y -> yqt [N][K] (transposed) ----------------
__global__ __launch_bounds__(256) void quant_kernel(const float* __restrict__ x,
                                                    const float* __restrict__ y,
                                                    unsigned int* __restrict__ xq_w,
                                                    signed char* __restrict__ yqt,
                                                    const float* __restrict__ partial) {
    __shared__ float ssc[8];
    __shared__ signed char tile[64][68];  // +4 pad (y path only)
    float sx, sy;
    load_scales(partial, sx, sy, ssc);
    int b = blockIdx.x;
    const int t = threadIdx.x;
    if (b < 2048) {
        int i = b * 256 + t;  // float4 index
        float4 v = ((const float4*)x)[i];
        unsigned b0 = (unsigned)quant1(v.x, sx) & 0xFF;
        unsigned b1 = (unsigned)quant1(v.y, sx) & 0xFF;
        unsigned b2 = (unsigned)quant1(v.z, sx) & 0xFF;
        unsigned b3 = (unsigned)quant1(v.w, sx) & 0xFF;
        xq_w[i] = b0 | (b1 << 8) | (b2 << 16) | (b3 << 24);
    } else {
        b -= 2048;
        const int n0 = (b & 127) * 64;
        const int k0 = (b >> 7) * 64;
        #pragma unroll
        for (int r = 0; r < 16; ++r) {
            int idx = r * 256 + t;
            int k = idx >> 6, n = idx & 63;
            float v = y[(size_t)(k0 + k) * N_DIM + n0 + n];
            tile[k][n] = (signed char)quant1(v, sy);
        }
        __syncthreads();
        #pragma unroll
        for (int r = 0; r < 4; ++r) {
            int idx = r * 256 + t;
            int n = idx >> 4, kw = idx & 15;
            unsigned wv = ((unsigned)(unsigned char)tile[kw * 4 + 0][n])
                        | ((unsigned)(unsigned char)tile[kw * 4 + 1][n] << 8)
                        | ((unsigned)(unsigned char)tile[kw * 4 + 2][n] << 16)
                        | ((unsigned)(unsigned char)tile[kw * 4 + 3][n] << 24);
            *(unsigned*)(yqt + (size_t)(n0 + n) * K_DIM + k0 + kw * 4) = wv;
        }
    }
}

// ---------------- int8 MFMA GEMM: 128x128 tile/block, 4 waves of 64x64 ----------------
// R17 structure frozen (best known): counted-vmcnt double-buffered staging,
// LDS-staged NT-store epilogue with lgkm-only barriers.
__global__ __launch_bounds__(256) void gemm_i8_kernel(const signed char* __restrict__ xq,
                                                      const signed char* __restrict__ yqt,
                                                      const float* __restrict__ partial,
                                                      float* __restrict__ out) {
    // union: 2 stage buffers (2 x 16KB: A[128][64] + B[128][64]) / epilogue (16.9KB)
    __shared__ __align__(16) unsigned char smem[32768];
    __shared__ float ssc[8];
    float (*epi)[132] = (float(*)[132])smem;

    const int tid = threadIdx.x;
    const int w = tid >> 6;
    const int lane = tid & 63;
    const int wr = w >> 1, wc = w & 1;

    // staging: waves 0,1 -> A rows (w&1)*64..+63; waves 2,3 -> B likewise.
    const signed char* gbase = (w < 2)
        ? (xq  + (size_t)(blockIdx.y * 128 + (w & 1) * 64 + (lane >> 2)) * K_DIM + (lane & 3) * 16)
        : (yqt + (size_t)(blockIdx.x * 128 + (w & 1) * 64 + (lane >> 2)) * K_DIM + (lane & 3) * 16);
    const int loff = ((w < 2) ? 0 : 8192) + (w & 1) * 64 * 64;

    // issue K-tile 0 DMA first, hide it under the scale reduction below
    #pragma unroll
    for (int c = 0; c < 4; ++c)
        async_lds16(gbase + (size_t)(c * 16) * K_DIM, (signed char*)smem + loff + c * 16 * 64);

    float sx, sy;
    load_scales(partial, sx, sy, ssc);     // __syncthreads inside is LDS/ssc-only
    const float scale = (sx * 1024.0f) * (sy / 1024.0f);   // reference's exact order

    const int frow = lane & 15;
    const int fk = (lane >> 4) * 16;

    i32x4 acc[4][4] = {};

    #pragma unroll
    for (int ks = 0; ks < 4; ++ks) {       // K = 4 * 64
        signed char* cur = (signed char*)smem + (ks & 1) * 16384;
        if (ks < 3) {                      // issue prefetch(ks+1) into other buffer
            signed char* nxt = (signed char*)smem + ((ks + 1) & 1) * 16384;
            #pragma unroll
            for (int c = 0; c < 4; ++c)
                async_lds16(gbase + (size_t)(c * 16) * K_DIM + (ks + 1) * 64,
                            nxt + loff + c * 16 * 64);
            bar_vm4();                     // own stage(ks) landed; prefetch stays in flight
        } else {
            bar_vm0();                     // last tile: drain everything
        }
        const signed char* ard = cur + (wr * 64 + frow) * 64 + fk;
        const signed char* brd = cur + 8192 + (wc * 64 + frow) * 64 + fk;
        i32x4 a[4], b[4];
        #pragma unroll
        for (int mi = 0; mi < 4; ++mi)
            a[mi] = *(const i32x4*)(ard + mi * 16 * 64);
        #pragma unroll
        for (int ni = 0; ni < 4; ++ni)
            b[ni] = *(const i32x4*)(brd + ni * 16 * 64);
        #pragma unroll
        for (int mi = 0; mi < 4; ++mi)
            #pragma unroll
            for (int ni = 0; ni < 4; ++ni)
                acc[mi][ni] = __builtin_amdgcn_mfma_i32_16x16x64_i8(a[mi], b[ni], acc[mi][ni], 0, 0, 0);
        bar_lds();                         // all waves' ds_reads of cur done before overwrite
    }

    // ---- LDS-staged epilogue: 4 chunks of 32 rows x 128 cols ----
    // MFMA C/D layout (16x16): col = lane&15, row = (lane>>4)*4 + r
    const int qrow = (lane >> 4) * 4;
    const int qcol = lane & 15;
    #pragma unroll
    for (int mi = 0; mi < 4; ++mi) {
        if (mi) bar_lds();                 // prior chunk's LDS reads done (lgkm only)
        #pragma unroll
        for (int ni = 0; ni < 4; ++ni)
            #pragma unroll
            for (int r = 0; r < 4; ++r)
                epi[wr * 16 + qrow + r][wc * 64 + ni * 16 + qcol] =
                    (float)acc[mi][ni][r] * scale;
        bar_lds();                         // writes visible; global stores stay in flight
        #pragma unroll
        for (int i = 0; i < 4; ++i) {
            int row = i * 8 + (tid >> 5);
            int col4 = tid & 31;
            f32x4 v = *(const f32x4*)&epi[row][col4 * 4];
            int grow = blockIdx.y * 128 + (row >> 4) * 64 + mi * 16 + (row & 15);
            int gcol = blockIdx.x * 128 + col4 * 4;
            __builtin_nontemporal_store(v, (f32x4*)&out[(size_t)grow * N_DIM + gcol]);
        }
    }
}

extern "C" void kernel_launch(void* const* d_in, const int* in_sizes, int n_in,
                              void* d_out, int out_size, void* d_ws, size_t ws_size,
                              hipStream_t stream) {
    const float* x = (const float*)d_in[0];   // [8192, 256]
    const float* y = (const float*)d_in[1];   // [256, 8192]
    float* out = (float*)d_out;               // [8192, 8192]

    unsigned char* ws = (unsigned char*)d_ws;
    float* partial = (float*)ws;                                  // 2048 floats (plain stores)
    signed char* xq = (signed char*)(ws + 16384);                 // 2 MB
    signed char* yqt = xq + (size_t)M_DIM * K_DIM;                // 2 MB

    absmax_kernel<<<dim3(1024, 2), 256, 0, stream>>>(x, y, partial);

    quant_kernel<<<2048 + 512, 256, 0, stream>>>(x, y, (unsigned int*)xq, yqt, partial);

    gemm_i8_kernel<<<dim3(N_DIM / 128, M_DIM / 128), 256, 0, stream>>>(xq, yqt, partial, out);
}

// Round 19
// 67.321 us; speedup vs baseline: 1.0163x; 1.0163x over previous
//
#include <hip/hip_runtime.h>

#define M_DIM 8192
#define N_DIM 8192
#define K_DIM 256

typedef __attribute__((ext_vector_type(4))) int i32x4;
typedef __attribute__((ext_vector_type(4))) float f32x4;

// Barrier that waits only on LDS ops (lgkmcnt) — global stores/DMA stay in flight.
__device__ __forceinline__ void bar_lds() {
    asm volatile("s_waitcnt lgkmcnt(0)" ::: "memory");
    __builtin_amdgcn_sched_barrier(0);
    __builtin_amdgcn_s_barrier();
}

// T4 counted wait: all but the newest 4 vector-mem ops (the just-issued prefetch)
// retired -> current K-tile's DMA landed; prefetch stays in flight across barrier.
__device__ __forceinline__ void bar_vm4() {
    asm volatile("s_waitcnt vmcnt(4)" ::: "memory");
    __builtin_amdgcn_sched_barrier(0);
    __builtin_amdgcn_s_barrier();
}

__device__ __forceinline__ void bar_vm0() {
    asm volatile("s_waitcnt vmcnt(0) lgkmcnt(0)" ::: "memory");
    __builtin_amdgcn_sched_barrier(0);
    __builtin_amdgcn_s_barrier();
}

__device__ __forceinline__ void async_lds16(const signed char* g, signed char* l) {
    __builtin_amdgcn_global_load_lds(
        (const __attribute__((address_space(1))) void*)g,
        (__attribute__((address_space(3))) void*)l, 16, 0, 0);
}

// ---------------- absmax partials: 256 blocks per tensor, plain stores, no atomics ----------------
__global__ __launch_bounds__(256) void absmax_kernel(const float* __restrict__ x,
                                                     const float* __restrict__ y,
                                                     float* __restrict__ partial) {
    const float* p = (blockIdx.y == 0) ? x : y;
    const int n4 = (M_DIM * K_DIM) / 4;
    const float4* p4 = (const float4*)p;
    float m = 0.0f;
    for (int i = blockIdx.x * 256 + threadIdx.x; i < n4; i += 256 * 256) {
        float4 v = p4[i];
        m = fmaxf(m, fmaxf(fmaxf(fabsf(v.x), fabsf(v.y)), fmaxf(fabsf(v.z), fabsf(v.w))));
    }
    for (int off = 32; off > 0; off >>= 1)
        m = fmaxf(m, __shfl_down(m, off));
    __shared__ float sm[4];
    int wid = threadIdx.x >> 6;
    if ((threadIdx.x & 63) == 0) sm[wid] = m;
    __syncthreads();
    if (threadIdx.x == 0)
        partial[blockIdx.y * 256 + blockIdx.x] = fmaxf(fmaxf(sm[0], sm[1]), fmaxf(sm[2], sm[3]));
}

// Dual block-wide max-reduce of the 2x256 partials -> scales. blockDim must be 256.
__device__ __forceinline__ void load_scales(const float* __restrict__ partial,
                                            float& sx, float& sy, float* ssc) {
    const int tid = threadIdx.x;
    float mx = partial[tid];
    float my = partial[256 + tid];
    for (int off = 32; off > 0; off >>= 1) {
        mx = fmaxf(mx, __shfl_down(mx, off));
        my = fmaxf(my, __shfl_down(my, off));
    }
    if ((tid & 63) == 0) { ssc[tid >> 6] = mx; ssc[4 + (tid >> 6)] = my; }
    __syncthreads();
    mx = fmaxf(fmaxf(ssc[0], ssc[1]), fmaxf(ssc[2], ssc[3]));
    my = fmaxf(fmaxf(ssc[4], ssc[5]), fmaxf(ssc[6], ssc[7]));
    sx = fmaxf(mx / 127.0f, 1e-12f);   // same op sequence as jnp
    sy = fmaxf(my / 127.0f, 1e-12f);
}

__device__ __forceinline__ int quant1(float v, float s) {
    float q = rintf(v / s);                      // RNE matches jnp.round; IEEE div matches t/s
    q = fmaxf(-127.0f, fminf(127.0f, q));
    return (int)q;
}

// ---------------- fused quantize: x -> xq [M][K], y -> yqt [N][K] (transposed) ----------------
__global__ __launch_bounds__(256) void quant_kernel(const float* __restrict__ x,
                                                    const float* __restrict__ y,
                                                    unsigned int* __restrict__ xq_w,
                                                    signed char* __restrict__ yqt,
                                                    const float* __restrict__ partial) {
    __shared__ float ssc[8];
    __shared__ signed char tile[64][68];  // +4 pad (y path only)
    float sx, sy;
    load_scales(partial, sx, sy, ssc);
    int b = blockIdx.x;
    const int t = threadIdx.x;
    if (b < 2048) {
        int i = b * 256 + t;  // float4 index
        float4 v = ((const float4*)x)[i];
        unsigned b0 = (unsigned)quant1(v.x, sx) & 0xFF;
        unsigned b1 = (unsigned)quant1(v.y, sx) & 0xFF;
        unsigned b2 = (unsigned)quant1(v.z, sx) & 0xFF;
        unsigned b3 = (unsigned)quant1(v.w, sx) & 0xFF;
        xq_w[i] = b0 | (b1 << 8) | (b2 << 16) | (b3 << 24);
    } else {
        b -= 2048;
        const int n0 = (b & 127) * 64;
        const int k0 = (b >> 7) * 64;
        #pragma unroll
        for (int r = 0; r < 16; ++r) {
            int idx = r * 256 + t;
            int k = idx >> 6, n = idx & 63;
            float v = y[(size_t)(k0 + k) * N_DIM + n0 + n];
            tile[k][n] = (signed char)quant1(v, sy);
        }
        __syncthreads();
        #pragma unroll
        for (int r = 0; r < 4; ++r) {
            int idx = r * 256 + t;
            int n = idx >> 4, kw = idx & 15;
            unsigned wv = ((unsigned)(unsigned char)tile[kw * 4 + 0][n])
                        | ((unsigned)(unsigned char)tile[kw * 4 + 1][n] << 8)
                        | ((unsigned)(unsigned char)tile[kw * 4 + 2][n] << 16)
                        | ((unsigned)(unsigned char)tile[kw * 4 + 3][n] << 24);
            *(unsigned*)(yqt + (size_t)(n0 + n) * K_DIM + k0 + kw * 4) = wv;
        }
    }
}

// ---------------- int8 MFMA GEMM: 128x128 tile/block, 4 waves of 64x64 ----------------
// Best-known structure (R17, 67.5us): counted-vmcnt (T4) double-buffered
// global_load_lds staging; LDS-staged NT-store epilogue with lgkm-only barriers.
__global__ __launch_bounds__(256) void gemm_i8_kernel(const signed char* __restrict__ xq,
                                                      const signed char* __restrict__ yqt,
                                                      const float* __restrict__ partial,
                                                      float* __restrict__ out) {
    // union: 2 stage buffers (2 x 16KB: A[128][64] + B[128][64]) / epilogue (16.9KB)
    __shared__ __align__(16) unsigned char smem[32768];
    __shared__ float ssc[8];
    float (*epi)[132] = (float(*)[132])smem;

    const int tid = threadIdx.x;
    const int w = tid >> 6;
    const int lane = tid & 63;
    const int wr = w >> 1, wc = w & 1;

    // staging: waves 0,1 -> A rows (w&1)*64..+63; waves 2,3 -> B likewise.
    const signed char* gbase = (w < 2)
        ? (xq  + (size_t)(blockIdx.y * 128 + (w & 1) * 64 + (lane >> 2)) * K_DIM + (lane & 3) * 16)
        : (yqt + (size_t)(blockIdx.x * 128 + (w & 1) * 64 + (lane >> 2)) * K_DIM + (lane & 3) * 16);
    const int loff = ((w < 2) ? 0 : 8192) + (w & 1) * 64 * 64;

    // issue K-tile 0 DMA first, hide it under the scale reduction below
    #pragma unroll
    for (int c = 0; c < 4; ++c)
        async_lds16(gbase + (size_t)(c * 16) * K_DIM, (signed char*)smem + loff + c * 16 * 64);

    float sx, sy;
    load_scales(partial, sx, sy, ssc);     // __syncthreads inside is LDS/ssc-only
    const float scale = (sx * 1024.0f) * (sy / 1024.0f);   // reference's exact order

    const int frow = lane & 15;
    const int fk = (lane >> 4) * 16;

    i32x4 acc[4][4] = {};

    #pragma unroll
    for (int ks = 0; ks < 4; ++ks) {       // K = 4 * 64
        signed char* cur = (signed char*)smem + (ks & 1) * 16384;
        if (ks < 3) {                      // issue prefetch(ks+1) into other buffer
            signed char* nxt = (signed char*)smem + ((ks + 1) & 1) * 16384;
            #pragma unroll
            for (int c = 0; c < 4; ++c)
                async_lds16(gbase + (size_t)(c * 16) * K_DIM + (ks + 1) * 64,
                            nxt + loff + c * 16 * 64);
            bar_vm4();                     // own stage(ks) landed; prefetch stays in flight
        } else {
            bar_vm0();                     // last tile: drain everything
        }
        const signed char* ard = cur + (wr * 64 + frow) * 64 + fk;
        const signed char* brd = cur + 8192 + (wc * 64 + frow) * 64 + fk;
        i32x4 a[4], b[4];
        #pragma unroll
        for (int mi = 0; mi < 4; ++mi)
            a[mi] = *(const i32x4*)(ard + mi * 16 * 64);
        #pragma unroll
        for (int ni = 0; ni < 4; ++ni)
            b[ni] = *(const i32x4*)(brd + ni * 16 * 64);
        #pragma unroll
        for (int mi = 0; mi < 4; ++mi)
            #pragma unroll
            for (int ni = 0; ni < 4; ++ni)
                acc[mi][ni] = __builtin_amdgcn_mfma_i32_16x16x64_i8(a[mi], b[ni], acc[mi][ni], 0, 0, 0);
        bar_lds();                         // all waves' ds_reads of cur done before overwrite
    }

    // ---- LDS-staged epilogue: 4 chunks of 32 rows x 128 cols ----
    // MFMA C/D layout (16x16): col = lane&15, row = (lane>>4)*4 + r
    const int qrow = (lane >> 4) * 4;
    const int qcol = lane & 15;
    #pragma unroll
    for (int mi = 0; mi < 4; ++mi) {
        if (mi) bar_lds();                 // prior chunk's LDS reads done (lgkm only)
        #pragma unroll
        for (int ni = 0; ni < 4; ++ni)
            #pragma unroll
            for (int r = 0; r < 4; ++r)
                epi[wr * 16 + qrow + r][wc * 64 + ni * 16 + qcol] =
                    (float)acc[mi][ni][r] * scale;
        bar_lds();                         // writes visible; global stores stay in flight
        #pragma unroll
        for (int i = 0; i < 4; ++i) {
            int row = i * 8 + (tid >> 5);
            int col4 = tid & 31;
            f32x4 v = *(const f32x4*)&epi[row][col4 * 4];
            int grow = blockIdx.y * 128 + (row >> 4) * 64 + mi * 16 + (row & 15);
            int gcol = blockIdx.x * 128 + col4 * 4;
            __builtin_nontemporal_store(v, (f32x4*)&out[(size_t)grow * N_DIM + gcol]);
        }
    }
}

extern "C" void kernel_launch(void* const* d_in, const int* in_sizes, int n_in,
                              void* d_out, int out_size, void* d_ws, size_t ws_size,
                              hipStream_t stream) {
    const float* x = (const float*)d_in[0];   // [8192, 256]
    const float* y = (const float*)d_in[1];   // [256, 8192]
    float* out = (float*)d_out;               // [8192, 8192]

    unsigned char* ws = (unsigned char*)d_ws;
    float* partial = (float*)ws;                                  // 512 floats (plain stores)
    signed char* xq = (signed char*)(ws + 4096);                  // 2 MB
    signed char* yqt = xq + (size_t)M_DIM * K_DIM;                // 2 MB

    absmax_kernel<<<dim3(256, 2), 256, 0, stream>>>(x, y, partial);

    quant_kernel<<<2048 + 512, 256, 0, stream>>>(x, y, (unsigned int*)xq, yqt, partial);

    gemm_i8_kernel<<<dim3(N_DIM / 128, M_DIM / 128), 256, 0, stream>>>(xq, yqt, partial, out);
}